// Round 1
// 195.386 us; speedup vs baseline: 1.0275x; 1.0275x over previous
//
#include <hip/hip_runtime.h>
#include <math.h>

#define BB 32
#define HH 56
#define WW 56
#define CC 256
#define NPIX (BB * HH * WW)   // 100352 pixels; CC=256 floats per pixel

// Kernel 1: per-pixel channel mean + max.
// 4 pixels per wave (4 independent float4 loads in flight -> hides HBM latency),
// 4 waves/block -> 16 pixels/block, NPIX/16 = 6272 blocks.
__global__ __launch_bounds__(256) void pool_kernel(const float* __restrict__ x,
                                                   float* __restrict__ pooled) {
    int wid  = blockIdx.x * 4 + (threadIdx.x >> 6);   // wave id, 4 pixels each
    int lane = threadIdx.x & 63;
    const float4* x4 = (const float4*)x;
    size_t base = ((size_t)wid << 8) | (size_t)lane;  // wid*4 pixels * 64 float4

    float s[4], m[4];
#pragma unroll
    for (int i = 0; i < 4; ++i) {
        float4 v = x4[base + (size_t)i * 64];
        s[i] = (v.x + v.y) + (v.z + v.w);
        m[i] = fmaxf(fmaxf(v.x, v.y), fmaxf(v.z, v.w));
    }
#pragma unroll
    for (int o = 32; o > 0; o >>= 1) {
#pragma unroll
        for (int i = 0; i < 4; ++i) {
            s[i] += __shfl_down(s[i], o, 64);
            m[i] = fmaxf(m[i], __shfl_down(m[i], o, 64));
        }
    }
    if (lane == 0) {
        float4* p4 = (float4*)pooled;   // pooled as [NPIX][2] floats
        p4[wid * 2]     = make_float4(s[0] * (1.0f / 256.0f), m[0],
                                      s[1] * (1.0f / 256.0f), m[1]);
        p4[wid * 2 + 1] = make_float4(s[2] * (1.0f / 256.0f), m[2],
                                      s[3] * (1.0f / 256.0f), m[3]);
    }
}

// Kernel 2: fused 7x7 'SAME' conv (2->1 ch) + bias + sigmoid + broadcast scale.
// One wave per pixel. Lanes 0..48 each take one conv tap from the L2-resident
// pooled map; 6-step shuffle reduce; broadcast; every lane scales its float4.
// The 1 KB x-load is issued FIRST so its (L3-hit) latency hides under the conv.
__global__ __launch_bounds__(256) void fused_kernel(const float* __restrict__ x,
                                                    const float* __restrict__ pooled,
                                                    const float* __restrict__ cw,
                                                    const float* __restrict__ cb,
                                                    float* __restrict__ out) {
    int pix  = blockIdx.x * 4 + (threadIdx.x >> 6);
    int lane = threadIdx.x & 63;

    size_t xi = ((size_t)pix << 6) | (size_t)lane;
    const float4* x4 = (const float4*)x;
    float4 v = x4[xi];                      // issue early; L3-resident after k1

    int b  = pix / (HH * WW);
    int hw = pix % (HH * WW);
    int h  = hw / WW;
    int w  = hw % WW;

    float acc = 0.0f;
    if (lane < 49) {
        int dh = lane / 7;                  // magic-mul, cheap
        int dw = lane - dh * 7;
        int ih = h + dh - 3;
        int iw = w + dw - 3;
        if (ih >= 0 && ih < HH && iw >= 0 && iw < WW) {
            const float2* p2 = (const float2*)pooled;
            float2 p = p2[(b * HH + ih) * WW + iw];
            float2 k = ((const float2*)cw)[lane];   // [7,7,2,1] HWIO -> float2[49]
            acc = fmaf(p.y, k.y, p.x * k.x);
        }
    }
#pragma unroll
    for (int o = 32; o > 0; o >>= 1) acc += __shfl_down(acc, o, 64);
    float a = __shfl(acc, 0, 64) + cb[0];
    a = 1.0f / (1.0f + expf(-a));

    v.x *= a; v.y *= a; v.z *= a; v.w *= a;
    ((float4*)out)[xi] = v;
}

extern "C" void kernel_launch(void* const* d_in, const int* in_sizes, int n_in,
                              void* d_out, int out_size, void* d_ws, size_t ws_size,
                              hipStream_t stream) {
    const float* x  = (const float*)d_in[0];
    const float* cw = (const float*)d_in[1];   // [7,7,2,1] HWIO
    const float* cb = (const float*)d_in[2];   // [1]
    float* out = (float*)d_out;

    float* pooled = (float*)d_ws;              // NPIX*2 floats = 0.8 MB

    // 1) pool: 4 pixels/wave, 16 pixels/block
    pool_kernel<<<NPIX / 16, 256, 0, stream>>>(x, pooled);
    // 2) conv+sigmoid+scale fused: one wave per pixel
    fused_kernel<<<NPIX / 4, 256, 0, stream>>>(x, pooled, cw, cb, out);
}